// Round 9
// baseline (1027.261 us; speedup 1.0000x reference)
//
#include <hip/hip_runtime.h>
#include <stdint.h>

// ---------------------------------------------------------------------------
// PointNet-style graph autoencoder, MI355X (gfx950).
//
// R15: occupancy attack. Measured law (R11-R14): waves/SIMD =
// floor(512 / (VGPR+AGPR)); acc[4][4]=64 AGPR pinned every GEMM at 4
// waves/SIMD (50%) while the edge kernel stalls ~35% on both pipes.
// Halve the tile: 32 rows x 256 cols, acc[2][4]=32 AGPR, uint2 gathers,
// af[2] -> unified ~82-85 -> 5-6 waves/SIMD. Zl shrinks to 256x36 shorts
// (18.4KB, 72B stride = 8B-aligned uint2, ~2-way banks). Same transform on
// gemm_node + decoder_fused: grid 782->1563 fixes their latency-starved
// 3-blocks/CU. Edge bound (256,6) [cap 85], node/decoder (256,5) [cap 102].
// Tripwire: WRITE_SIZE must stay ~62MB (spill detector), VGPR<=70.
// Pipeline per chunk unchanged (R11 family): pack -> Al[buf], bfv[4] live
// across ONE lgkm-only barrier, gather prefetch in flight, 8 MFMAs.
// ---------------------------------------------------------------------------

using bf16x8 = __attribute__((ext_vector_type(8))) short;
using f32x4  = __attribute__((ext_vector_type(4))) float;

#define AB_STRIDE 40      // shorts per staged A row (32 k + 8 pad) -> 16B aligned
#define ABUF32    1280    // shorts per A buffer (32 * AB_STRIDE)
#define Z2STRIDE  36      // shorts per Z column (32 rows + 4 pad; 72B: 8B-aligned)

#define BARRIER_NOVM() asm volatile("s_waitcnt lgkmcnt(0)\n\ts_barrier" ::: "memory")

__device__ __forceinline__ float b2f(uint32_t v16) {          // bf16 bits -> f32
    return __uint_as_float(v16 << 16);
}
__device__ __forceinline__ float b2f_hi(uint32_t w) {         // high bf16 of word
    return __uint_as_float(w & 0xffff0000u);
}
__device__ __forceinline__ uint16_t f2b(float f) {            // f32 -> bf16 (RNE)
    uint32_t u = __float_as_uint(f);
    u += 0x7fffu + ((u >> 16) & 1u);
    return (uint16_t)(u >> 16);
}
#if __has_builtin(__builtin_amdgcn_cvt_pk_bf16_f32)
__device__ __forceinline__ uint32_t pack2bf(float lo, float hi) {
    auto r = __builtin_amdgcn_cvt_pk_bf16_f32(lo, hi);   // RNE
    uint32_t u; __builtin_memcpy(&u, &r, 4); return u;
}
#else
__device__ __forceinline__ uint32_t pack2bf(float lo, float hi) {
    return (uint32_t)f2b(lo) | ((uint32_t)f2b(hi) << 16);
}
#endif
// packed bf16 relu: max_i16(x,0) == bf16(relu) for finite bf16 (sign-mag order)
__device__ __forceinline__ uint32_t pk_relu_bf2(uint32_t w) {
    uint32_t r;
    asm("v_pk_max_i16 %0, %1, 0" : "=v"(r) : "v"(w));
    return r;
}
// monotone float<->uint mapping for atomicMax-based segment_max
__device__ __forceinline__ uint32_t encf(float f) {
    uint32_t u = __float_as_uint(f);
    return (u & 0x80000000u) ? ~u : (u | 0x80000000u);
}
__device__ __forceinline__ float decf(uint32_t k) {
    uint32_t u = (k & 0x80000000u) ? (k & 0x7fffffffu) : ~k;
    return __uint_as_float(u);
}

// ---------------------------------------------------------------------------
// Dtype detection. flags[0]=1 if float tensors are fp32 (else bf16),
// flags[1]=1 if edge_index is int64 (else int32).
// ---------------------------------------------------------------------------
__global__ void detect_fmt(const uint32_t* __restrict__ x,
                           const uint32_t* __restrict__ ei,
                           uint32_t* __restrict__ flags) {
    if (threadIdx.x == 0 && blockIdx.x == 0) {
        int plaus = 0;
        for (int i = 0; i < 64; i++) {
            uint32_t v = x[i];
            uint32_t e = (v >> 23) & 0xffu;
            if (v == 0u || (e >= 96u && e <= 150u)) plaus++;
        }
        flags[0] = (plaus >= 48) ? 1u : 0u;
        int zeros = 0;
        for (int i = 0; i < 16; i++)
            if (ei[2 * i + 1] == 0u) zeros++;
        flags[1] = (zeros == 16) ? 1u : 0u;
    }
}

struct ConvArgs {
    const void* src[13];
    uint32_t dstOff[13];
    uint32_t n[13];
};

// batched small float tensors -> canonical bf16 arena
__global__ __launch_bounds__(256) void convert_small(
        ConvArgs a, uint16_t* __restrict__ dstBase, const uint32_t* __restrict__ flags) {
    bool isf32 = flags[0] != 0u;
    int t = blockIdx.y;
    int i = blockIdx.x * 256 + threadIdx.x;
    if (i >= (int)a.n[t]) return;
    uint16_t* d = dstBase + a.dstOff[t];
    d[i] = isf32 ? f2b(((const float*)a.src[t])[i]) : ((const uint16_t*)a.src[t])[i];
}

// ---------------------------------------------------------------------------
// Counting sort of edges by dst (parallel 3-kernel scan).
// ---------------------------------------------------------------------------
// fused: agg := enc(+0) everywhere; hist := 0 (both uint4-wide)
__global__ __launch_bounds__(256) void init_hist_agg(
        uint32_t* __restrict__ agg, int n4, int* __restrict__ hist, int N) {
    int i = blockIdx.x * 256 + threadIdx.x;
    if (i < n4) {
        uint4 v = {0x80000000u, 0x80000000u, 0x80000000u, 0x80000000u};
        ((uint4*)agg)[i] = v;
    }
    int i4 = i * 4;
    if (i4 + 3 < N) {
        uint4 z = {0, 0, 0, 0};
        ((uint4*)hist)[i] = z;
    } else if (i4 < N) {
        for (int j = i4; j < N; j++) hist[j] = 0;
    }
}

__global__ __launch_bounds__(256) void hist_dst(
        const int* __restrict__ ei_raw, int E, int* __restrict__ hist,
        const uint32_t* __restrict__ flags) {
    bool i64 = flags[1] != 0u;
    int e = blockIdx.x * 256 + threadIdx.x;
    if (e < E) {
        int d = i64 ? ei_raw[2 * (E + e)] : ei_raw[E + e];
        atomicAdd(&hist[d], 1);
    }
}

// per-1024-chunk exclusive scan + chunk totals
__global__ __launch_bounds__(1024) void scan_partial(
        const int* __restrict__ hist, int* __restrict__ cursor,
        int* __restrict__ part, int N) {
    __shared__ int wsum[16];
    int tid = threadIdx.x, lane = tid & 63, wid = tid >> 6;
    int base = blockIdx.x * 1024;
    int v = (base + tid < N) ? hist[base + tid] : 0;
    int x = v;
#pragma unroll
    for (int s = 1; s < 64; s <<= 1) {
        int t = __shfl_up(x, s, 64);
        if (lane >= s) x += t;
    }
    if (lane == 63) wsum[wid] = x;
    __syncthreads();
    if (wid == 0 && lane < 16) {
        int w = wsum[lane];
#pragma unroll
        for (int s = 1; s < 16; s <<= 1) {
            int t = __shfl_up(w, s, 64);
            if (lane >= s) w += t;
        }
        wsum[lane] = w;
    }
    __syncthreads();
    int wbase = (wid > 0) ? wsum[wid - 1] : 0;
    if (base + tid < N) cursor[base + tid] = x - v + wbase;
    if (tid == 0) part[blockIdx.x] = wsum[15];
}

// exclusive scan of chunk totals (B <= 1024)
__global__ __launch_bounds__(1024) void scan_carry(
        const int* __restrict__ part, int* __restrict__ carry, int B) {
    __shared__ int wsum[16];
    int tid = threadIdx.x, lane = tid & 63, wid = tid >> 6;
    int v = (tid < B) ? part[tid] : 0;
    int x = v;
#pragma unroll
    for (int s = 1; s < 64; s <<= 1) {
        int t = __shfl_up(x, s, 64);
        if (lane >= s) x += t;
    }
    if (lane == 63) wsum[wid] = x;
    __syncthreads();
    if (wid == 0 && lane < 16) {
        int w = wsum[lane];
#pragma unroll
        for (int s = 1; s < 16; s <<= 1) {
            int t = __shfl_up(w, s, 64);
            if (lane >= s) w += t;
        }
        wsum[lane] = w;
    }
    __syncthreads();
    int wbase = (wid > 0) ? wsum[wid - 1] : 0;
    if (tid < B) carry[tid] = x - v + wbase;
}

__global__ __launch_bounds__(1024) void scan_add(
        int* __restrict__ cursor, const int* __restrict__ carry, int N) {
    int i = blockIdx.x * 1024 + threadIdx.x;
    if (i < N) cursor[i] += carry[blockIdx.x];
}

__global__ __launch_bounds__(256) void scatter_edges(
        const int* __restrict__ ei_raw, int E, int* __restrict__ cursor,
        int* __restrict__ esrc, int* __restrict__ edst,
        const uint32_t* __restrict__ flags) {
    bool i64 = flags[1] != 0u;
    int e = blockIdx.x * 256 + threadIdx.x;
    if (e < E) {
        int s = i64 ? ei_raw[2 * e] : ei_raw[e];
        int d = i64 ? ei_raw[2 * (E + e)] : ei_raw[E + e];
        int p = atomicAdd(&cursor[d], 1);
        esrc[p] = s;
        edst[p] = d;
    }
}

// ---------------------------------------------------------------------------
// Transpose+chunk-tile the 6 [256x256] B-matrices into WT (32-k chunks):
//   WT[w][ (k>>5)*8192 + n*32 + (k&31) ] = W[k*256 + n]
// ---------------------------------------------------------------------------
__global__ __launch_bounds__(256) void transpose_w(
        const uint16_t* s0, const uint16_t* s1, const uint16_t* s2,
        const uint16_t* s3, const uint16_t* s4, const uint16_t* s5,
        uint16_t* dst) {
    const uint16_t* srcs[6] = {s0, s1, s2, s3, s4, s5};
    const uint16_t* src = srcs[blockIdx.y];
    uint16_t* d = dst + (size_t)blockIdx.y * 65536;
    int k = blockIdx.x;          // grid.x = 256
    int n = threadIdx.x;
    d[(k >> 5) * 8192 + n * 32 + (k & 31)] = src[k * 256 + n];
}

// Q[i][c] = sum_d pos[i][d] * wpos[d][c]   (wpos = wA rows 256..258)
// vectorized: 8 rows/block, 32 threads/row, uint4 (16B) stores.
__global__ __launch_bounds__(256) void pos_proj(
        const uint16_t* pos, const uint16_t* wpos, uint16_t* Q, int N) {
    int t = threadIdx.x;
    int r = t >> 5, c8 = (t & 31) * 8;
    int i = blockIdx.x * 8 + r;
    if (i >= N) return;
    uint4 wv0 = *(const uint4*)(wpos + c8);
    uint4 wv1 = *(const uint4*)(wpos + 256 + c8);
    uint4 wv2 = *(const uint4*)(wpos + 512 + c8);
    float p0 = b2f(pos[i * 3 + 0]);
    float p1 = b2f(pos[i * 3 + 1]);
    float p2 = b2f(pos[i * 3 + 2]);
    uint32_t w0[4] = {wv0.x, wv0.y, wv0.z, wv0.w};
    uint32_t w1[4] = {wv1.x, wv1.y, wv1.z, wv1.w};
    uint32_t w2[4] = {wv2.x, wv2.y, wv2.z, wv2.w};
    uint32_t o[4];
#pragma unroll
    for (int j = 0; j < 4; j++) {
        float lo = p0 * b2f(w0[j] & 0xffffu) + p1 * b2f(w1[j] & 0xffffu) + p2 * b2f(w2[j] & 0xffffu);
        float hi = p0 * b2f_hi(w0[j]) + p1 * b2f_hi(w1[j]) + p2 * b2f_hi(w2[j]);
        o[j] = pack2bf(lo, hi);
    }
    uint4 ov = {o[0], o[1], o[2], o[3]};
    *(uint4*)(Q + (size_t)i * 256 + c8) = ov;
}

// ---------------------------------------------------------------------------
// Node GEMM, 32-row tile (acc[2][4]=32 AGPR -> 5+ waves/SIMD), R11 pipeline:
// A dbuf in LDS with reg prefetch across one lgkm-only barrier; B fragments
// from L2-hot WT pre-barrier, live across. Grid = (M+31)/32 = 1563 blocks.
//   AMODE 1: A is agg-encoded u32 -> decf -> bf16; REINIT=1 writes enc(0)
//            back after the K-loop (rows owned by this block).
//   AMODE 2: A is raw x: f32 (convert) or bf16 (pass-through) per flags[0]
// Output: bf16 +bias +Q.
// ---------------------------------------------------------------------------
template <int AMODE, int REINIT>
__global__ __launch_bounds__(256, 5) void gemm_node(
        const void* __restrict__ Araw, const uint16_t* __restrict__ BT,
        const uint16_t* __restrict__ bias, const uint16_t* __restrict__ Qadd,
        void* __restrict__ out, int M, const uint32_t* __restrict__ flags,
        uint32_t* __restrict__ aggwb) {
    __shared__ __align__(16) uint16_t Al[2 * ABUF32];   // 5120 B
    int tid = threadIdx.x;
    int tileM = blockIdx.x;
    int wave = tid >> 6, lane = tid & 63, lrow = lane & 15, quad = lane >> 4;
    int row = tid >> 3, kq = (tid & 7) * 4;             // 4 elements / thread
    f32x4 acc[2][4] = {};

    int rg = tileM * 32 + row;
    bool rok = rg < M;
    int rgc = rok ? rg : (M - 1);            // clamp: keep vm counts uniform
    bool isf32 = false;
    if (AMODE == 2) isf32 = flags[0] != 0u;

    const uint16_t* a16 = (const uint16_t*)Araw + (size_t)rgc * 256 + kq;
    const uint32_t* a32 = (const uint32_t*)Araw + (size_t)rgc * 256 + kq;
    const uint16_t* bfrag = BT + (wave * 64 + lrow) * 32 + quad * 8;
    uint16_t* awr = Al + row * AB_STRIDE + kq;
    const uint16_t* ard = Al + lrow * AB_STRIDE + quad * 8;

    // prefetch A chunk 0 (live across the barrier)
    uint4 p0 = {0, 0, 0, 0};
    if (AMODE == 1) {
        p0 = *(const uint4*)a32;
    } else {
        if (isf32) p0 = *(const uint4*)a32;
        else { uint2 t0 = *(const uint2*)a16; p0.x = t0.x; p0.y = t0.y; }
    }

#pragma unroll
    for (int kc = 0; kc < 256; kc += 32) {
        int buf = (kc >> 5) & 1;
        // stage A chunk -> Al[buf], converting per AMODE
        uint2 wv;
        if (AMODE == 1) {
            wv.x = pack2bf(decf(p0.x), decf(p0.y));
            wv.y = pack2bf(decf(p0.z), decf(p0.w));
        } else if (isf32) {
            wv.x = pack2bf(__uint_as_float(p0.x), __uint_as_float(p0.y));
            wv.y = pack2bf(__uint_as_float(p0.z), __uint_as_float(p0.w));
        } else {
            wv.x = p0.x; wv.y = p0.y;
        }
        *(uint2*)(awr + buf * ABUF32) = wv;
        // B fragments for this chunk, straight from L2 (live across barrier)
        const uint16_t* bp = bfrag + (kc >> 5) * 8192;
        bf16x8 bfv[4];
#pragma unroll
        for (int c = 0; c < 4; c++) bfv[c] = *(const bf16x8*)(bp + c * 512);
        // prefetch next A chunk (stays in flight across the barrier)
        if (kc < 224) {
            if (AMODE == 1) {
                p0 = *(const uint4*)(a32 + kc + 32);
            } else if (isf32) {
                p0 = *(const uint4*)(a32 + kc + 32);
            } else {
                uint2 t0 = *(const uint2*)(a16 + kc + 32);
                p0.x = t0.x; p0.y = t0.y;
            }
        }
        BARRIER_NOVM();
        const uint16_t* ar = ard + buf * ABUF32;
        bf16x8 af[2];
#pragma unroll
        for (int r = 0; r < 2; r++) af[r] = *(const bf16x8*)(ar + r * 16 * AB_STRIDE);
#pragma unroll
        for (int r = 0; r < 2; r++)
#pragma unroll
            for (int c = 0; c < 4; c++)
                acc[r][c] = __builtin_amdgcn_mfma_f32_16x16x32_bf16(af[r], bfv[c], acc[r][c], 0, 0, 0);
    }

    // agg re-init writeback (layer-2 Gs build): this block owns these rows
    if (AMODE == 1 && REINIT && rok) {
        uint32_t* wb = aggwb + (size_t)rg * 256 + kq;
        uint4 z = {0x80000000u, 0x80000000u, 0x80000000u, 0x80000000u};
#pragma unroll
        for (int kc = 0; kc < 256; kc += 32)
            *(uint4*)(wb + kc) = z;
    }

#pragma unroll
    for (int c = 0; c < 4; c++) {
        int col = wave * 64 + c * 16 + lrow;
        float bv = b2f(bias[col]);
#pragma unroll
        for (int r = 0; r < 2; r++) {
#pragma unroll
            for (int i = 0; i < 4; i++) {
                int rw = tileM * 32 + r * 16 + quad * 4 + i;
                if (rw >= M) continue;
                float v = acc[r][c][i] + bv;
                v += b2f(Qadd[(size_t)rw * 256 + col]);
                ((uint16_t*)out)[(size_t)rw * 256 + col] = f2b(v);
            }
        }
    }
}

// ---------------------------------------------------------------------------
// Fused decoder, 32-row tile: out = relu(dec(agg) @ wd1 + bd1) @ wd2 + bd2.
// GEMM1 output tile t (32x256) parked in LDS in chunked A-layout
// [8][32][AB_STRIDE] (20480 B); GEMM2 reads af straight from t (no staging,
// no barriers). Grid 1563.
// ---------------------------------------------------------------------------
__global__ __launch_bounds__(256, 5) void decoder_fused(
        const uint32_t* __restrict__ agg, const uint16_t* __restrict__ BT1,
        const uint16_t* __restrict__ bias1, const uint16_t* __restrict__ BT2,
        const uint16_t* __restrict__ bias2, void* __restrict__ out, int M,
        const uint32_t* __restrict__ flags) {
    __shared__ __align__(16) uint16_t SM[8 * ABUF32];   // 20480 B; [0..1]=Al dbuf
    uint16_t* Al = SM;
    int tid = threadIdx.x;
    int tileM = blockIdx.x;
    int wave = tid >> 6, lane = tid & 63, lrow = lane & 15, quad = lane >> 4;
    int row = tid >> 3, kq = (tid & 7) * 4;
    f32x4 acc[2][4] = {};

    int rg = tileM * 32 + row;
    bool rok = rg < M;
    int rgc = rok ? rg : (M - 1);
    bool isf32 = flags[0] != 0u;

    const uint32_t* a32 = agg + (size_t)rgc * 256 + kq;
    const uint16_t* bfrag1 = BT1 + (wave * 64 + lrow) * 32 + quad * 8;
    const uint16_t* bfrag2 = BT2 + (wave * 64 + lrow) * 32 + quad * 8;
    uint16_t* awr = Al + row * AB_STRIDE + kq;
    const uint16_t* ard = Al + lrow * AB_STRIDE + quad * 8;

    uint4 p0 = *(const uint4*)a32;

    // ---- GEMM1: t = relu(dec(agg) @ wd1 + bd1) ----
#pragma unroll
    for (int kc = 0; kc < 256; kc += 32) {
        int buf = (kc >> 5) & 1;
        uint2 wv;
        wv.x = pack2bf(decf(p0.x), decf(p0.y));
        wv.y = pack2bf(decf(p0.z), decf(p0.w));
        *(uint2*)(awr + buf * ABUF32) = wv;
        const uint16_t* bp = bfrag1 + (kc >> 5) * 8192;
        bf16x8 bfv[4];
#pragma unroll
        for (int c = 0; c < 4; c++) bfv[c] = *(const bf16x8*)(bp + c * 512);
        if (kc < 224) p0 = *(const uint4*)(a32 + kc + 32);
        BARRIER_NOVM();
        const uint16_t* ar = ard + buf * ABUF32;
        bf16x8 af[2];
#pragma unroll
        for (int r = 0; r < 2; r++) af[r] = *(const bf16x8*)(ar + r * 16 * AB_STRIDE);
#pragma unroll
        for (int r = 0; r < 2; r++)
#pragma unroll
            for (int c = 0; c < 4; c++)
                acc[r][c] = __builtin_amdgcn_mfma_f32_16x16x32_bf16(af[r], bfv[c], acc[r][c], 0, 0, 0);
    }

    BARRIER_NOVM();   // all waves done reading Al before t overwrites SM[0..1]

    // ---- scatter t = f2b(relu(acc + bd1)) into chunked A-layout ----
#pragma unroll
    for (int c = 0; c < 4; c++) {
        int col = wave * 64 + c * 16 + lrow;
        float bv = b2f(bias1[col]);
        uint16_t* tb = SM + (col >> 5) * ABUF32 + (col & 31);
#pragma unroll
        for (int r = 0; r < 2; r++) {
#pragma unroll
            for (int i = 0; i < 4; i++) {
                int rr = r * 16 + quad * 4 + i;
                tb[rr * AB_STRIDE] = f2b(fmaxf(acc[r][c][i] + bv, 0.f));
            }
            acc[r][c] = (f32x4){0.f, 0.f, 0.f, 0.f};   // reset for GEMM2
        }
    }
    BARRIER_NOVM();   // t complete and visible

    // ---- GEMM2: out = t @ wd2 + bd2 (no barriers; t is read-only) ----
#pragma unroll
    for (int kc = 0; kc < 256; kc += 32) {
        const uint16_t* tb = SM + (kc >> 5) * ABUF32;
        const uint16_t* bp = bfrag2 + (kc >> 5) * 8192;
        bf16x8 af[2], bfv[4];
#pragma unroll
        for (int c = 0; c < 4; c++) bfv[c] = *(const bf16x8*)(bp + c * 512);
#pragma unroll
        for (int r = 0; r < 2; r++)
            af[r] = *(const bf16x8*)(tb + (r * 16 + lrow) * AB_STRIDE + quad * 8);
#pragma unroll
        for (int r = 0; r < 2; r++)
#pragma unroll
            for (int c = 0; c < 4; c++)
                acc[r][c] = __builtin_amdgcn_mfma_f32_16x16x32_bf16(af[r], bfv[c], acc[r][c], 0, 0, 0);
    }

#pragma unroll
    for (int c = 0; c < 4; c++) {
        int col = wave * 64 + c * 16 + lrow;
        float bv = b2f(bias2[col]);
#pragma unroll
        for (int r = 0; r < 2; r++) {
#pragma unroll
            for (int i = 0; i < 4; i++) {
                int rw = tileM * 32 + r * 16 + quad * 4 + i;
                if (rw >= M) continue;
                float v = acc[r][c][i] + bv;
                if (isf32) ((float*)out)[(size_t)rw * 256 + col] = v;
                else       ((uint16_t*)out)[(size_t)rw * 256 + col] = f2b(v);
            }
        }
    }
}

// ---------------------------------------------------------------------------
// Edge kernel over dst-SORTED edges, 32-edge tile (acc[2][4]=32 AGPR ->
// target 6 waves/SIMD at (256,6)). Per chunk: pack pk_relu(bf16(g-q)) ->
// Al[buf] (uint2/thread); bfv[4] from L2-hot WT pre-barrier (live across);
// gather prefetch uint2 (live across); ONE lgkm-only barrier; af[2];
// 8 MFMAs. Epilogue: Z parked col-major (Z2STRIDE=36, 8B-aligned), 32-bit
// run-boundary mask, run-max scan, one coalesced atomicMax per (run,col).
// ---------------------------------------------------------------------------
__global__ __launch_bounds__(256, 6) void edge_gemm_agg(
        const uint16_t* __restrict__ Gs16, const uint16_t* __restrict__ Qb,
        const uint16_t* __restrict__ BT, const uint16_t* __restrict__ bias,
        const int* __restrict__ esrc, const int* __restrict__ edst, int E,
        uint32_t* __restrict__ agg) {
    __shared__ __align__(16) uint16_t SM[256 * Z2STRIDE];    // 18432 B
    uint16_t* Al = SM;                       // dbuf: 2 x ABUF32 = 5120 B
    uint16_t* Zl = SM;                       // overlay: col-major 256 x Z2STRIDE
    __shared__ int sdst[32];
    __shared__ uint32_t smask;
    int tid = threadIdx.x;
    int ebase = blockIdx.x * 32;
    int evalid = (E - ebase < 32) ? (E - ebase) : 32;
    if (tid < 32) sdst[tid] = (tid < evalid) ? edst[ebase + tid] : 0;  // wave 0

    int wave = tid >> 6, lane = tid & 63, lrow = lane & 15, quad = lane >> 4;
    int row = tid >> 3, kq = (tid & 7) * 4;
    int er = (row < evalid) ? row : (evalid - 1);
    int s = esrc[ebase + er];
    int d = edst[ebase + er];
    const uint16_t* gbase = Gs16 + (size_t)s * 256 + kq;
    const uint16_t* qbase = Qb   + (size_t)d * 256 + kq;
    const uint16_t* bfrag = BT + (wave * 64 + lrow) * 32 + quad * 8;
    uint16_t* awr = Al + row * AB_STRIDE + kq;
    const uint16_t* ard = Al + lrow * AB_STRIDE + quad * 8;

    f32x4 acc[2][4] = {};
    uint2 g = *(const uint2*)gbase;          // gathers for chunk 0
    uint2 q = *(const uint2*)qbase;

#pragma unroll
    for (int kc = 0; kc < 256; kc += 32) {
        int buf = (kc >> 5) & 1;
        // pack current chunk: pk_relu(bf16(g - q)) -> Al[buf]
        uint32_t gw[2] = {g.x, g.y};
        uint32_t qw[2] = {q.x, q.y};
        uint32_t mw[2];
#pragma unroll
        for (int j = 0; j < 2; j++) {
            float lo = b2f(gw[j] & 0xffffu) - b2f(qw[j] & 0xffffu);
            float hi = b2f_hi(gw[j]) - b2f_hi(qw[j]);
            mw[j] = pk_relu_bf2(pack2bf(lo, hi));
        }
        uint2 wv = {mw[0], mw[1]};
        *(uint2*)(awr + buf * ABUF32) = wv;
        // B(k) fragments from L2-hot WT -- issued pre-barrier, live across
        const uint16_t* bp = bfrag + (kc >> 5) * 8192;
        bf16x8 bfv[4];
#pragma unroll
        for (int c = 0; c < 4; c++) bfv[c] = *(const bf16x8*)(bp + c * 512);
        // prefetch gathers(k+1): fly across the barrier, land during MFMAs
        if (kc < 224) {
            g = *(const uint2*)(gbase + kc + 32);
            q = *(const uint2*)(qbase + kc + 32);
        }
        BARRIER_NOVM();
        const uint16_t* ar = ard + buf * ABUF32;
        bf16x8 af[2];
#pragma unroll
        for (int r = 0; r < 2; r++) af[r] = *(const bf16x8*)(ar + r * 16 * AB_STRIDE);
#pragma unroll
        for (int r = 0; r < 2; r++)
#pragma unroll
            for (int c = 0; c < 4; c++)
                acc[r][c] = __builtin_amdgcn_mfma_f32_16x16x32_bf16(af[r], bfv[c], acc[r][c], 0, 0, 0);
    }
    __syncthreads();          // all waves done reading Al before Z overlays it

    // park z = acc + bias in LDS col-major as bf16 (RNE monotone: commutes w/ max)
    float bv[4];
#pragma unroll
    for (int c = 0; c < 4; c++) bv[c] = b2f(bias[wave * 64 + c * 16 + lrow]);
#pragma unroll
    for (int c = 0; c < 4; c++) {
        int col = wave * 64 + c * 16 + lrow;
#pragma unroll
        for (int r = 0; r < 2; r++) {
            uint2 z4 = {pack2bf(acc[r][c][0] + bv[c], acc[r][c][1] + bv[c]),
                        pack2bf(acc[r][c][2] + bv[c], acc[r][c][3] + bv[c])};
            *(uint2*)&Zl[col * Z2STRIDE + r * 16 + quad * 4] = z4;
        }
    }
    // run-boundary mask (uniform): bit r set where sdst[r] != sdst[r-1]
    if (wave == 0) {
        int li = lane & 31;
        int d0 = sdst[li];
        int dp = (li > 0) ? sdst[li - 1] : -1;
        uint64_t m = __ballot((lane < 32) && (d0 != dp));
        if (lane == 0) smask = (uint32_t)m;
    }
    __syncthreads();

    // run-max over sorted dst, one coalesced atomic per (run, col)
    uint32_t mask = smask;
    int col = tid;
    const uint16_t* zc = &Zl[col * Z2STRIDE];
    float run = 0.f;
#pragma unroll 4
    for (int gi = 0; gi < 8; gi++) {
        int rbase = gi * 4;
        if (rbase >= evalid) break;
        uint2 z4 = *(const uint2*)&zc[rbase];
        float vv[4] = {b2f(z4.x & 0xffffu), b2f_hi(z4.x),
                       b2f(z4.y & 0xffffu), b2f_hi(z4.y)};
#pragma unroll
        for (int i = 0; i < 4; i++) {
            int r = rbase + i;
            if (r >= evalid) break;
            if (r == 0) {
                run = vv[0];
            } else if ((mask >> r) & 1u) {
                int dp = sdst[r - 1];
                atomicMax(agg + (size_t)dp * 256 + col, encf(run));
                run = vv[i];
            } else {
                run = fmaxf(run, vv[i]);
            }
        }
    }
    if (evalid > 0)
        atomicMax(agg + (size_t)sdst[evalid - 1] * 256 + col, encf(run));
}

// ---------------------------------------------------------------------------
extern "C" void kernel_launch(void* const* d_in, const int* in_sizes, int n_in,
                              void* d_out, int out_size, void* d_ws, size_t ws_size,
                              hipStream_t stream) {
    const void* x_raw   = d_in[0];
    const void* pos_raw = d_in[1];
    const int*  ei_raw  = (const int*)d_in[2];

    int N = in_sizes[0] / 256;     // 50000
    int E = in_sizes[2] / 2;       // 800000

    // ---- workspace layout (256B-aligned chunks) ----
    char* ws = (char*)d_ws;
    size_t off = 0;
    auto alloc = [&](size_t bytes) { void* p = ws + off; off += (bytes + 255) & ~(size_t)255; return p; };

    uint32_t* flags = (uint32_t*)alloc(256);
    uint16_t* WT    = (uint16_t*)alloc(6 * 65536 * sizeof(uint16_t));          // 768 KB
    const uint32_t POS_OFF = 0;
    const uint32_t W1A_OFF = POS_OFF + (uint32_t)(N * 3);
    const uint32_t W2A_OFF = W1A_OFF + 66304;
    const uint32_t W1B_OFF = W2A_OFF + 66304;
    const uint32_t W2B_OFF = W1B_OFF + 65536;
    const uint32_t WD1_OFF = W2B_OFF + 65536;
    const uint32_t WD2_OFF = WD1_OFF + 65536;
    const uint32_t B1A_OFF = WD2_OFF + 65536;
    const uint32_t B1B_OFF = B1A_OFF + 256;
    const uint32_t B2A_OFF = B1B_OFF + 256;
    const uint32_t B2B_OFF = B2A_OFF + 256;
    const uint32_t BD1_OFF = B2B_OFF + 256;
    const uint32_t BD2_OFF = BD1_OFF + 256;
    const uint32_t ARENA_ELEMS = BD2_OFF + 256;
    uint16_t* arena = (uint16_t*)alloc((size_t)ARENA_ELEMS * 2);
    int*      hist  = (int*)alloc((size_t)N * 4);
    int*      curs  = (int*)alloc((size_t)N * 4);
    int*      part  = (int*)alloc(1024 * 4);
    int*      carry = (int*)alloc(1024 * 4);
    int*      esrc  = (int*)alloc((size_t)E * 4);
    int*      edst  = (int*)alloc((size_t)E * 4);
    uint16_t* Qb    = (uint16_t*)alloc((size_t)N * 256 * 2);                   // 25.6 MB
    uint16_t* Gs    = (uint16_t*)alloc((size_t)N * 256 * 2);                   // 25.6 MB (bf16)
    uint32_t* agg   = (uint32_t*)alloc((size_t)N * 256 * 4);                   // 51.2 MB

    uint16_t* posb = arena + POS_OFF;
    uint16_t* w1a = arena + W1A_OFF, * w2a = arena + W2A_OFF;
    uint16_t* w1b = arena + W1B_OFF, * w2b = arena + W2B_OFF;
    uint16_t* wd1 = arena + WD1_OFF, * wd2 = arena + WD2_OFF;
    uint16_t* b1a = arena + B1A_OFF, * b1b = arena + B1B_OFF;
    uint16_t* b2a = arena + B2A_OFF, * b2b = arena + B2B_OFF;
    uint16_t* bd1 = arena + BD1_OFF, * bd2 = arena + BD2_OFF;

    int n4      = N * 64;
    int nbElem  = (n4 + 255) / 256;
    int nbNode  = (N + 31) / 32;
    int nbEdge  = (E + 31) / 32;
    int nbE256  = (E + 255) / 256;
    int nbPos   = (N + 7) / 8;
    int nbScan  = (N + 1023) / 1024;

    // ---- detection + canonicalization (weights/biases/pos only) ----
    detect_fmt<<<1, 64, 0, stream>>>((const uint32_t*)x_raw, (const uint32_t*)ei_raw, flags);

    ConvArgs ca;
    ca.src[0] = pos_raw;  ca.dstOff[0] = POS_OFF; ca.n[0] = (uint32_t)(N * 3);
    ca.src[1] = d_in[3];  ca.dstOff[1] = W1A_OFF; ca.n[1] = 66304;
    ca.src[2] = d_in[7];  ca.dstOff[2] = W2A_OFF; ca.n[2] = 66304;
    ca.src[3] = d_in[5];  ca.dstOff[3] = W1B_OFF; ca.n[3] = 65536;
    ca.src[4] = d_in[9];  ca.dstOff[4] = W2B_OFF; ca.n[4] = 65536;
    ca.src[5] = d_in[11]; ca.dstOff[5] = WD1_OFF; ca.n[5] = 65536;
    ca.src[6] = d_in[13]; ca.dstOff[6] = WD2_OFF; ca.n[6] = 65536;
    ca.src[7] = d_in[4];  ca.dstOff[7] = B1A_OFF; ca.n[7] = 256;
    ca.src[8] = d_in[6];  ca.dstOff[8] = B1B_OFF; ca.n[8] = 256;
    ca.src[9] = d_in[8];  ca.dstOff[9] = B2A_OFF; ca.n[9] = 256;
    ca.src[10] = d_in[10]; ca.dstOff[10] = B2B_OFF; ca.n[10] = 256;
    ca.src[11] = d_in[12]; ca.dstOff[11] = BD1_OFF; ca.n[11] = 256;
    ca.src[12] = d_in[14]; ca.dstOff[12] = BD2_OFF; ca.n[12] = 256;
    {
        uint32_t maxn = (uint32_t)(N * 3);
        dim3 g((maxn + 255) / 256, 13);
        convert_small<<<g, 256, 0, stream>>>(ca, arena, flags);
    }

    // ---- counting sort of edges by dst (once, reused by both layers) ----
    init_hist_agg<<<nbElem, 256, 0, stream>>>(agg, n4, hist, N);
    hist_dst<<<nbE256, 256, 0, stream>>>(ei_raw, E, hist, flags);
    scan_partial<<<nbScan, 1024, 0, stream>>>(hist, curs, part, N);
    scan_carry<<<1, 1024, 0, stream>>>(part, carry, nbScan);
    scan_add<<<nbScan, 1024, 0, stream>>>(curs, carry, N);
    scatter_edges<<<nbE256, 256, 0, stream>>>(ei_raw, E, curs, esrc, edst, flags);

    transpose_w<<<dim3(256, 6), 256, 0, stream>>>(w1a, w1b, w2a, w2b, wd1, wd2, WT);

    // ---- layer 1 ----
    pos_proj<<<nbPos, 256, 0, stream>>>(posb, w1a + 65536, Qb, N);
    gemm_node<2, 0><<<nbNode, 256, 0, stream>>>(
        x_raw, WT + 0 * 65536, b1a, Qb, Gs, N, flags, nullptr);
    edge_gemm_agg<<<nbEdge, 256, 0, stream>>>(Gs, Qb, WT + 1 * 65536, b1b, esrc, edst, E, agg);

    // ---- layer 2 (A = encoded agg, decoded in staging; re-inits agg) ----
    pos_proj<<<nbPos, 256, 0, stream>>>(posb, w2a + 65536, Qb, N);
    gemm_node<1, 1><<<nbNode, 256, 0, stream>>>(
        agg, WT + 2 * 65536, b2a, Qb, Gs, N, flags, agg);
    edge_gemm_agg<<<nbEdge, 256, 0, stream>>>(Gs, Qb, WT + 3 * 65536, b2b, esrc, edst, E, agg);

    // ---- fused decoder ----
    decoder_fused<<<nbNode, 256, 0, stream>>>(
        agg, WT + 4 * 65536, bd1, WT + 5 * 65536, bd2, d_out, N, flags);
}